// Round 1
// baseline (1808.697 us; speedup 1.0000x reference)
//
#include <hip/hip_runtime.h>

#define HIDDEN 256
#define NGRAPH 1024

// Pass 1: per-graph scalar sum of squares + counts.
// One wave (64 lanes) per node row: 64 * float4 = 256 floats, fully coalesced.
__global__ void k_segss(const float* __restrict__ x, const int* __restrict__ batch,
                        float* __restrict__ ss, float* __restrict__ cnt, int n_nodes) {
    const int lane   = threadIdx.x & 63;
    const int wave   = (int)((blockIdx.x * blockDim.x + threadIdx.x) >> 6);
    const int nwaves = (int)((gridDim.x * blockDim.x) >> 6);

    for (int node = wave; node < n_nodes; node += nwaves) {
        const float4 v = *reinterpret_cast<const float4*>(
            x + (size_t)node * HIDDEN + (size_t)lane * 4);
        float s = v.x * v.x + v.y * v.y + v.z * v.z + v.w * v.w;
        #pragma unroll
        for (int off = 32; off > 0; off >>= 1)
            s += __shfl_xor(s, off);
        if (lane == 0) {
            const int g = batch[node];
            atomicAdd(&ss[g], s);
            atomicAdd(&cnt[g], 1.0f);
        }
    }
}

// Pass 2: inv_rms per graph (tiny).
__global__ void k_inv(const float* __restrict__ ss, const float* __restrict__ cnt,
                      float* __restrict__ inv, int g_count) {
    const int g = blockIdx.x * blockDim.x + threadIdx.x;
    if (g < g_count) {
        const float c    = fmaxf(cnt[g], 1.0f);
        const float mean = ss[g] / (c * (float)HIDDEN);
        inv[g] = 1.0f / sqrtf(mean + 1e-6f);
    }
}

// Pass 3: out[n][h] = weight[h] * x[n][h] * inv[batch[n]].
// Same wave-per-row layout as pass 1.
__global__ void k_norm(const float* __restrict__ x, const int* __restrict__ batch,
                       const float* __restrict__ w, const float* __restrict__ inv,
                       float* __restrict__ out, int n_nodes) {
    const int lane   = threadIdx.x & 63;
    const int wave   = (int)((blockIdx.x * blockDim.x + threadIdx.x) >> 6);
    const int nwaves = (int)((gridDim.x * blockDim.x) >> 6);

    const float4 wv = *reinterpret_cast<const float4*>(w + (size_t)lane * 4);

    for (int node = wave; node < n_nodes; node += nwaves) {
        const int   g = batch[node];
        const float r = inv[g];
        const float4 v = *reinterpret_cast<const float4*>(
            x + (size_t)node * HIDDEN + (size_t)lane * 4);
        float4 o;
        o.x = v.x * wv.x * r;
        o.y = v.y * wv.y * r;
        o.z = v.z * wv.z * r;
        o.w = v.w * wv.w * r;
        *reinterpret_cast<float4*>(out + (size_t)node * HIDDEN + (size_t)lane * 4) = o;
    }
}

extern "C" void kernel_launch(void* const* d_in, const int* in_sizes, int n_in,
                              void* d_out, int out_size, void* d_ws, size_t ws_size,
                              hipStream_t stream) {
    const float* x     = (const float*)d_in[0];
    const int*   batch = (const int*)d_in[1];
    const float* w     = (const float*)d_in[2];
    float*       out   = (float*)d_out;
    const int n_nodes  = in_sizes[1];

    float* ss  = (float*)d_ws;       // [NGRAPH]
    float* cnt = ss + NGRAPH;        // [NGRAPH]
    float* inv = cnt + NGRAPH;       // [NGRAPH]

    // ws is poisoned 0xAA and never re-poisoned between replays: zero it here.
    hipMemsetAsync(d_ws, 0, 2 * NGRAPH * sizeof(float), stream);

    // 4096 blocks x 256 threads = 16384 waves; grid-stride over 1M nodes.
    k_segss<<<4096, 256, 0, stream>>>(x, batch, ss, cnt, n_nodes);
    k_inv<<<NGRAPH / 256, 256, 0, stream>>>(ss, cnt, inv, NGRAPH);
    k_norm<<<4096, 256, 0, stream>>>(x, batch, w, inv, out, n_nodes);
}

// Round 2
// 668.770 us; speedup vs baseline: 2.7045x; 2.7045x over previous
//
#include <hip/hip_runtime.h>

#define HIDDEN 256
#define NGRAPH 1024

// Pass 1: per-graph scalar sum of squares + counts.
// batch is SORTED. Each wave owns a contiguous slice of rows; per-lane
// register accumulation across rows, flush (shuffle-reduce + 2 atomics)
// only when the graph id changes (~1-2x per wave). One wave reads a full
// 256-float row per iteration (64 lanes x float4 = 1 KiB, coalesced).
__global__ void k_segss(const float* __restrict__ x, const int* __restrict__ batch,
                        float* __restrict__ ss, float* __restrict__ cnt, int n_nodes) {
    const int lane   = threadIdx.x & 63;
    const int wave   = (int)((blockIdx.x * blockDim.x + threadIdx.x) >> 6);
    const int nwaves = (int)((gridDim.x * blockDim.x) >> 6);

    const int slice = (n_nodes + nwaves - 1) / nwaves;
    const int begin = wave * slice;
    const int end   = min(n_nodes, begin + slice);
    if (begin >= end) return;

    int   cur_g = batch[begin];   // wave-uniform (same addr all lanes -> broadcast)
    float acc   = 0.0f;           // per-lane partial sum of squares
    int   cn    = 0;              // rows accumulated (wave-uniform)

    for (int node = begin; node < end; ++node) {
        const int g = batch[node];
        if (g != cur_g) {          // wave-uniform branch (sorted batch)
            float s = acc;
            #pragma unroll
            for (int off = 32; off > 0; off >>= 1)
                s += __shfl_xor(s, off);
            if (lane == 0) {
                atomicAdd(&ss[cur_g], s);
                atomicAdd(&cnt[cur_g], (float)cn);
            }
            cur_g = g;
            acc   = 0.0f;
            cn    = 0;
        }
        const float4 v = *reinterpret_cast<const float4*>(
            x + (size_t)node * HIDDEN + (size_t)lane * 4);
        acc += v.x * v.x + v.y * v.y + v.z * v.z + v.w * v.w;
        ++cn;
    }
    // final flush
    {
        float s = acc;
        #pragma unroll
        for (int off = 32; off > 0; off >>= 1)
            s += __shfl_xor(s, off);
        if (lane == 0) {
            atomicAdd(&ss[cur_g], s);
            atomicAdd(&cnt[cur_g], (float)cn);
        }
    }
}

// Pass 2: inv_rms per graph (tiny).
__global__ void k_inv(const float* __restrict__ ss, const float* __restrict__ cnt,
                      float* __restrict__ inv, int g_count) {
    const int g = blockIdx.x * blockDim.x + threadIdx.x;
    if (g < g_count) {
        const float c    = fmaxf(cnt[g], 1.0f);
        const float mean = ss[g] / (c * (float)HIDDEN);
        inv[g] = 1.0f / sqrtf(mean + 1e-6f);
    }
}

// Pass 3: out[n][h] = weight[h] * x[n][h] * inv[batch[n]].
__global__ void k_norm(const float* __restrict__ x, const int* __restrict__ batch,
                       const float* __restrict__ w, const float* __restrict__ inv,
                       float* __restrict__ out, int n_nodes) {
    const int lane   = threadIdx.x & 63;
    const int wave   = (int)((blockIdx.x * blockDim.x + threadIdx.x) >> 6);
    const int nwaves = (int)((gridDim.x * blockDim.x) >> 6);

    const float4 wv = *reinterpret_cast<const float4*>(w + (size_t)lane * 4);

    for (int node = wave; node < n_nodes; node += nwaves) {
        const int   g = batch[node];
        const float r = inv[g];
        const float4 v = *reinterpret_cast<const float4*>(
            x + (size_t)node * HIDDEN + (size_t)lane * 4);
        float4 o;
        o.x = v.x * wv.x * r;
        o.y = v.y * wv.y * r;
        o.z = v.z * wv.z * r;
        o.w = v.w * wv.w * r;
        *reinterpret_cast<float4*>(out + (size_t)node * HIDDEN + (size_t)lane * 4) = o;
    }
}

extern "C" void kernel_launch(void* const* d_in, const int* in_sizes, int n_in,
                              void* d_out, int out_size, void* d_ws, size_t ws_size,
                              hipStream_t stream) {
    const float* x     = (const float*)d_in[0];
    const int*   batch = (const int*)d_in[1];
    const float* w     = (const float*)d_in[2];
    float*       out   = (float*)d_out;
    const int n_nodes  = in_sizes[1];

    float* ss  = (float*)d_ws;       // [NGRAPH]
    float* cnt = ss + NGRAPH;        // [NGRAPH]
    float* inv = cnt + NGRAPH;       // [NGRAPH]

    // ws is poisoned 0xAA and never re-poisoned between replays: zero it here.
    hipMemsetAsync(d_ws, 0, 2 * NGRAPH * sizeof(float), stream);

    // 1024 blocks x 256 threads = 4096 waves; each wave owns ~244 contiguous rows.
    k_segss<<<1024, 256, 0, stream>>>(x, batch, ss, cnt, n_nodes);
    k_inv<<<NGRAPH / 256, 256, 0, stream>>>(ss, cnt, inv, NGRAPH);
    k_norm<<<4096, 256, 0, stream>>>(x, batch, w, inv, out, n_nodes);
}

// Round 3
// 626.143 us; speedup vs baseline: 2.8886x; 1.0681x over previous
//
#include <hip/hip_runtime.h>

#define HIDDEN 256
#define NGRAPH 1024
#define EPS 1e-6f

__device__ __forceinline__ float row_ss(const float4 v) {
    return v.x * v.x + v.y * v.y + v.z * v.z + v.w * v.w;
}

__device__ __forceinline__ void flush_ss(float acc, int cn, int g, int lane,
                                         float* __restrict__ ss, float* __restrict__ cnt) {
    #pragma unroll
    for (int off = 32; off > 0; off >>= 1)
        acc += __shfl_xor(acc, off);
    if (lane == 0) {
        atomicAdd(&ss[g], acc);
        atomicAdd(&cnt[g], (float)cn);
    }
}

// Pass 1: per-graph scalar sum of squares + counts. batch is SORTED.
// Each wave owns a contiguous slice; 8-row uniform-chunk fast path gives
// 8 independent float4 loads per iteration (no per-row branches).
__global__ void k_segss(const float* __restrict__ x, const int* __restrict__ batch,
                        float* __restrict__ ss, float* __restrict__ cnt, int n_nodes) {
    const int lane   = threadIdx.x & 63;
    const int wave   = (int)((blockIdx.x * blockDim.x + threadIdx.x) >> 6);
    const int nwaves = (int)((gridDim.x * blockDim.x) >> 6);

    const int slice = (n_nodes + nwaves - 1) / nwaves;
    const int begin = wave * slice;
    const int end   = min(n_nodes, begin + slice);
    if (begin >= end) return;

    int   cur_g = batch[begin];   // wave-uniform broadcast load
    float acc   = 0.0f;
    int   cn    = 0;
    int   node  = begin;

    while (node < end) {
        if (node + 8 <= end && batch[node + 7] == cur_g) {
            // sorted + endpoints equal => all 8 rows belong to cur_g
            float4 v[8];
            #pragma unroll
            for (int i = 0; i < 8; ++i)
                v[i] = *reinterpret_cast<const float4*>(
                    x + (size_t)(node + i) * HIDDEN + (size_t)lane * 4);
            #pragma unroll
            for (int i = 0; i < 8; ++i)
                acc += row_ss(v[i]);
            cn += 8;
            node += 8;
        } else {
            const int g = batch[node];
            if (g != cur_g) {
                flush_ss(acc, cn, cur_g, lane, ss, cnt);
                cur_g = g; acc = 0.0f; cn = 0;
            }
            const float4 v = *reinterpret_cast<const float4*>(
                x + (size_t)node * HIDDEN + (size_t)lane * 4);
            acc += row_ss(v);
            ++cn; ++node;
        }
    }
    flush_ss(acc, cn, cur_g, lane, ss, cnt);
}

__device__ __forceinline__ float make_r(const float* __restrict__ ss,
                                        const float* __restrict__ cnt, int g) {
    const float c    = fmaxf(cnt[g], 1.0f);
    const float mean = ss[g] / (c * (float)HIDDEN);
    return 1.0f / sqrtf(mean + EPS);
}

// Pass 2: out[n][h] = w[h] * x[n][h] * inv_rms[batch[n]], inv computed inline
// on g-change (once per ~slice). Same 8-row uniform-chunk structure.
__global__ void k_norm(const float* __restrict__ x, const int* __restrict__ batch,
                       const float* __restrict__ w, const float* __restrict__ ss,
                       const float* __restrict__ cnt, float* __restrict__ out,
                       int n_nodes) {
    const int lane   = threadIdx.x & 63;
    const int wave   = (int)((blockIdx.x * blockDim.x + threadIdx.x) >> 6);
    const int nwaves = (int)((gridDim.x * blockDim.x) >> 6);

    const int slice = (n_nodes + nwaves - 1) / nwaves;
    const int begin = wave * slice;
    const int end   = min(n_nodes, begin + slice);
    if (begin >= end) return;

    const float4 wv = *reinterpret_cast<const float4*>(w + (size_t)lane * 4);

    int   cur_g = batch[begin];
    float r     = make_r(ss, cnt, cur_g);
    int   node  = begin;

    while (node < end) {
        if (node + 8 <= end && batch[node + 7] == cur_g) {
            float4 v[8];
            #pragma unroll
            for (int i = 0; i < 8; ++i)
                v[i] = *reinterpret_cast<const float4*>(
                    x + (size_t)(node + i) * HIDDEN + (size_t)lane * 4);
            #pragma unroll
            for (int i = 0; i < 8; ++i) {
                float4 o;
                o.x = v[i].x * wv.x * r;
                o.y = v[i].y * wv.y * r;
                o.z = v[i].z * wv.z * r;
                o.w = v[i].w * wv.w * r;
                *reinterpret_cast<float4*>(
                    out + (size_t)(node + i) * HIDDEN + (size_t)lane * 4) = o;
            }
            node += 8;
        } else {
            const int g = batch[node];
            if (g != cur_g) { cur_g = g; r = make_r(ss, cnt, cur_g); }
            const float4 v = *reinterpret_cast<const float4*>(
                x + (size_t)node * HIDDEN + (size_t)lane * 4);
            float4 o;
            o.x = v.x * wv.x * r;
            o.y = v.y * wv.y * r;
            o.z = v.z * wv.z * r;
            o.w = v.w * wv.w * r;
            *reinterpret_cast<float4*>(
                out + (size_t)node * HIDDEN + (size_t)lane * 4) = o;
            ++node;
        }
    }
}

extern "C" void kernel_launch(void* const* d_in, const int* in_sizes, int n_in,
                              void* d_out, int out_size, void* d_ws, size_t ws_size,
                              hipStream_t stream) {
    const float* x     = (const float*)d_in[0];
    const int*   batch = (const int*)d_in[1];
    const float* w     = (const float*)d_in[2];
    float*       out   = (float*)d_out;
    const int n_nodes  = in_sizes[1];

    float* ss  = (float*)d_ws;       // [NGRAPH]
    float* cnt = ss + NGRAPH;        // [NGRAPH]

    // ws is poisoned 0xAA and never re-poisoned between replays: zero it here.
    hipMemsetAsync(d_ws, 0, 2 * NGRAPH * sizeof(float), stream);

    // segss: 2048 blocks x 256 = 8192 waves, ~123 contiguous rows each.
    k_segss<<<2048, 256, 0, stream>>>(x, batch, ss, cnt, n_nodes);
    // norm: 4096 blocks x 256 = 16384 waves, ~62 contiguous rows each.
    k_norm<<<4096, 256, 0, stream>>>(x, batch, w, ss, cnt, out, n_nodes);
}

// Round 4
// 565.851 us; speedup vs baseline: 3.1964x; 1.1066x over previous
//
#include <hip/hip_runtime.h>

#define HIDDEN 256
#define NGRAPH 1024
#define EPS 1e-6f

// One block per graph (batch sorted => graph g owns contiguous rows [start,end)).
// Phase A: stream-read the graph's ~1MB slab, per-lane sum-of-squares, block reduce.
// Phase B: re-read the slab in REVERSE sweep order (most-recent lines first -> L3
// hits), scale by weight * inv_rms, write out.
//
// The 96 KB static LDS forces 1 block/CU: only 256 blocks resident, so the live
// slab footprint (256 x ~1MB = 256MB) ~fits the Infinity Cache, making phase B's
// re-read cache-served instead of a second HBM pass. No atomics, no workspace.
__global__ __launch_bounds__(512) void k_fused(
    const float* __restrict__ x, const int* __restrict__ batch,
    const float* __restrict__ w, float* __restrict__ out, int n_nodes) {

    __shared__ float smem[24576];   // 96 KB; smem[0..7] used for the block reduce

    const int g    = (int)blockIdx.x;
    const int tid  = (int)threadIdx.x;
    const int lane = tid & 63;
    const int wid  = tid >> 6;      // 0..7

    // Binary-search graph bounds (wave-uniform broadcast loads, ~40 total).
    int lo = 0, hi = n_nodes;
    while (lo < hi) { int m = (lo + hi) >> 1; if (batch[m] < g) lo = m + 1; else hi = m; }
    const int start = lo;
    int lo2 = start, hi2 = n_nodes;
    while (lo2 < hi2) { int m = (lo2 + hi2) >> 1; if (batch[m] < g + 1) lo2 = m + 1; else hi2 = m; }
    const int count = lo2 - start;
    if (count <= 0) return;         // block-uniform: safe w.r.t. __syncthreads below

    const int nsweep = (count + 63) >> 6;   // 8 waves x 8 rows per sweep

    // ---- Phase A: sum of squares ----
    float acc = 0.0f;
    for (int s = 0; s < nsweep; ++s) {
        const int base = (s << 6) + (wid << 3);
        if (base + 8 <= count) {
            float4 v[8];
            #pragma unroll
            for (int k = 0; k < 8; ++k)
                v[k] = *reinterpret_cast<const float4*>(
                    x + (size_t)(start + base + k) * HIDDEN + (size_t)lane * 4);
            #pragma unroll
            for (int k = 0; k < 8; ++k)
                acc += v[k].x * v[k].x + v[k].y * v[k].y + v[k].z * v[k].z + v[k].w * v[k].w;
        } else {
            for (int r = base; r < count; ++r) {
                const float4 v = *reinterpret_cast<const float4*>(
                    x + (size_t)(start + r) * HIDDEN + (size_t)lane * 4);
                acc += v.x * v.x + v.y * v.y + v.z * v.z + v.w * v.w;
            }
        }
    }
    #pragma unroll
    for (int off = 32; off > 0; off >>= 1)
        acc += __shfl_xor(acc, off);
    if (lane == 0) smem[wid] = acc;
    __syncthreads();

    float total = 0.0f;
    #pragma unroll
    for (int k = 0; k < 8; ++k) total += smem[k];
    const float mean = total / ((float)count * (float)HIDDEN);
    const float rr   = 1.0f / sqrtf(mean + EPS);

    // ---- Phase B: normalize, reverse sweep order for cache recency ----
    const float4 wv = *reinterpret_cast<const float4*>(w + (size_t)lane * 4);
    for (int s = nsweep - 1; s >= 0; --s) {
        const int base = (s << 6) + (wid << 3);
        if (base + 8 <= count) {
            float4 v[8];
            #pragma unroll
            for (int k = 0; k < 8; ++k)
                v[k] = *reinterpret_cast<const float4*>(
                    x + (size_t)(start + base + k) * HIDDEN + (size_t)lane * 4);
            #pragma unroll
            for (int k = 0; k < 8; ++k) {
                float4 o;
                o.x = v[k].x * wv.x * rr;
                o.y = v[k].y * wv.y * rr;
                o.z = v[k].z * wv.z * rr;
                o.w = v[k].w * wv.w * rr;
                *reinterpret_cast<float4*>(
                    out + (size_t)(start + base + k) * HIDDEN + (size_t)lane * 4) = o;
            }
        } else {
            for (int r = base; r < count; ++r) {
                const float4 v = *reinterpret_cast<const float4*>(
                    x + (size_t)(start + r) * HIDDEN + (size_t)lane * 4);
                float4 o;
                o.x = v.x * wv.x * rr;
                o.y = v.y * wv.y * rr;
                o.z = v.z * wv.z * rr;
                o.w = v.w * wv.w * rr;
                *reinterpret_cast<float4*>(
                    out + (size_t)(start + r) * HIDDEN + (size_t)lane * 4) = o;
            }
        }
    }
}

extern "C" void kernel_launch(void* const* d_in, const int* in_sizes, int n_in,
                              void* d_out, int out_size, void* d_ws, size_t ws_size,
                              hipStream_t stream) {
    const float* x     = (const float*)d_in[0];
    const int*   batch = (const int*)d_in[1];
    const float* w     = (const float*)d_in[2];
    float*       out   = (float*)d_out;
    const int n_nodes  = in_sizes[1];

    // One block per graph; 512 threads = 8 waves; 96 KB LDS -> 1 block/CU.
    k_fused<<<NGRAPH, 512, 0, stream>>>(x, batch, w, out, n_nodes);
}

// Round 6
// 459.717 us; speedup vs baseline: 3.9344x; 1.2309x over previous
//
#include <hip/hip_runtime.h>

#define HIDDEN 256
#define NGRAPH 1024
#define EPS 1e-6f

typedef float f32x4 __attribute__((ext_vector_type(4)));

// One block per graph (batch sorted => graph g owns contiguous rows [start,end)).
// Phase A: stream-read the graph's ~1MB slab (cacheable: lines re-used in
//          phase B), per-lane sum-of-squares, block reduce.
// Phase B: re-read the slab in REVERSE sweep order (most-recently-read lines
//          first -> L3 recency hits) with NON-TEMPORAL loads (a missed line is
//          dead after use: don't evict other blocks' phase-A lines), scale by
//          weight * inv_rms, write out with NON-TEMPORAL stores (the 1 GB write
//          stream must not evict cached x lines).
//
// The 96 KB static LDS forces 1 block/CU: 256 resident blocks x ~1MB slab
// ~= the 256 MB Infinity Cache, so phase-B re-reads can be cache-served.
// No atomics, no workspace.
__global__ __launch_bounds__(512) void k_fused(
    const float* __restrict__ x, const int* __restrict__ batch,
    const float* __restrict__ w, float* __restrict__ out, int n_nodes) {

    __shared__ float smem[24576];   // 96 KB; smem[0..7] used for the block reduce

    const int g    = (int)blockIdx.x;
    const int tid  = (int)threadIdx.x;
    const int lane = tid & 63;
    const int wid  = tid >> 6;      // 0..7

    // Binary-search graph bounds (wave-uniform broadcast loads, ~40 total).
    int lo = 0, hi = n_nodes;
    while (lo < hi) { int m = (lo + hi) >> 1; if (batch[m] < g) lo = m + 1; else hi = m; }
    const int start = lo;
    int lo2 = start, hi2 = n_nodes;
    while (lo2 < hi2) { int m = (lo2 + hi2) >> 1; if (batch[m] < g + 1) lo2 = m + 1; else hi2 = m; }
    const int count = lo2 - start;
    if (count <= 0) return;         // block-uniform: safe w.r.t. __syncthreads below

    const int nsweep = (count + 63) >> 6;   // 8 waves x 8 rows per sweep

    // ---- Phase A: sum of squares (cacheable reads) ----
    float acc = 0.0f;
    for (int s = 0; s < nsweep; ++s) {
        const int base = (s << 6) + (wid << 3);
        if (base + 8 <= count) {
            f32x4 v[8];
            #pragma unroll
            for (int k = 0; k < 8; ++k)
                v[k] = *reinterpret_cast<const f32x4*>(
                    x + (size_t)(start + base + k) * HIDDEN + (size_t)lane * 4);
            #pragma unroll
            for (int k = 0; k < 8; ++k)
                acc += v[k].x * v[k].x + v[k].y * v[k].y + v[k].z * v[k].z + v[k].w * v[k].w;
        } else {
            for (int r = base; r < count; ++r) {
                const f32x4 v = *reinterpret_cast<const f32x4*>(
                    x + (size_t)(start + r) * HIDDEN + (size_t)lane * 4);
                acc += v.x * v.x + v.y * v.y + v.z * v.z + v.w * v.w;
            }
        }
    }
    #pragma unroll
    for (int off = 32; off > 0; off >>= 1)
        acc += __shfl_xor(acc, off);
    if (lane == 0) smem[wid] = acc;
    __syncthreads();

    float total = 0.0f;
    #pragma unroll
    for (int k = 0; k < 8; ++k) total += smem[k];
    const float mean = total / ((float)count * (float)HIDDEN);
    const float rr   = 1.0f / sqrtf(mean + EPS);

    // ---- Phase B: normalize; reverse sweep order; NT loads + NT stores ----
    const f32x4 wv = *reinterpret_cast<const f32x4*>(w + (size_t)lane * 4);
    for (int s = nsweep - 1; s >= 0; --s) {
        const int base = (s << 6) + (wid << 3);
        if (base + 8 <= count) {
            f32x4 v[8];
            #pragma unroll
            for (int k = 0; k < 8; ++k)
                v[k] = __builtin_nontemporal_load(reinterpret_cast<const f32x4*>(
                    x + (size_t)(start + base + k) * HIDDEN + (size_t)lane * 4));
            #pragma unroll
            for (int k = 0; k < 8; ++k) {
                f32x4 o;
                o.x = v[k].x * wv.x * rr;
                o.y = v[k].y * wv.y * rr;
                o.z = v[k].z * wv.z * rr;
                o.w = v[k].w * wv.w * rr;
                __builtin_nontemporal_store(o, reinterpret_cast<f32x4*>(
                    out + (size_t)(start + base + k) * HIDDEN + (size_t)lane * 4));
            }
        } else {
            for (int r = base; r < count; ++r) {
                const f32x4 v = __builtin_nontemporal_load(reinterpret_cast<const f32x4*>(
                    x + (size_t)(start + r) * HIDDEN + (size_t)lane * 4));
                f32x4 o;
                o.x = v.x * wv.x * rr;
                o.y = v.y * wv.y * rr;
                o.z = v.z * wv.z * rr;
                o.w = v.w * wv.w * rr;
                __builtin_nontemporal_store(o, reinterpret_cast<f32x4*>(
                    out + (size_t)(start + r) * HIDDEN + (size_t)lane * 4));
            }
        }
    }
}

extern "C" void kernel_launch(void* const* d_in, const int* in_sizes, int n_in,
                              void* d_out, int out_size, void* d_ws, size_t ws_size,
                              hipStream_t stream) {
    const float* x     = (const float*)d_in[0];
    const int*   batch = (const int*)d_in[1];
    const float* w     = (const float*)d_in[2];
    float*       out   = (float*)d_out;
    const int n_nodes  = in_sizes[1];

    // One block per graph; 512 threads = 8 waves; 96 KB LDS -> 1 block/CU.
    k_fused<<<NGRAPH, 512, 0, stream>>>(x, batch, w, out, n_nodes);
}

// Round 7
// 443.402 us; speedup vs baseline: 4.0791x; 1.0368x over previous
//
#include <hip/hip_runtime.h>

#define HIDDEN 256
#define NGRAPH 1024
#define EPS 1e-6f
#define STAGE_ROWS 152   // rows of the slab head staged in LDS (152 KB)

typedef float f32x4 __attribute__((ext_vector_type(4)));

// One block per graph (batch sorted => graph g owns contiguous rows [start,end)).
// Phase A: stream-read the graph's ~1MB slab (cacheable), per-lane sum of
//          squares, block reduce. The FIRST 152 rows are additionally staged
//          into LDS: they have the worst phase-B recency (re-read last) and
//          would be guaranteed L3 misses.
// Phase B: re-read the slab in REVERSE sweep order (most-recently-read lines
//          first -> L3 recency hits). Rows 0..151 come from LDS; the rest via
//          NON-TEMPORAL loads (dead after use: don't evict other blocks'
//          pending lines). Output written with NON-TEMPORAL stores so the 1 GB
//          write stream doesn't evict cached x lines.
//
// The ~152 KB static LDS forces 1 block/CU: 256 resident blocks x ~1MB slab
// ~= the 256 MB Infinity Cache, so phase-B re-reads are largely cache-served.
// Sweep->wave mapping is identical in both phases, so each wave reads back its
// own LDS writes (no extra barrier needed beyond the reduce's syncthreads).
__global__ __launch_bounds__(512) void k_fused(
    const float* __restrict__ x, const int* __restrict__ batch,
    const float* __restrict__ w, float* __restrict__ out, int n_nodes) {

    __shared__ float smem[STAGE_ROWS * HIDDEN + 8];   // 152 KB stage + reduce scratch

    const int g    = (int)blockIdx.x;
    const int tid  = (int)threadIdx.x;
    const int lane = tid & 63;
    const int wid  = tid >> 6;      // 0..7

    // Binary-search graph bounds (wave-uniform broadcast loads, ~40 total).
    int lo = 0, hi = n_nodes;
    while (lo < hi) { int m = (lo + hi) >> 1; if (batch[m] < g) lo = m + 1; else hi = m; }
    const int start = lo;
    int lo2 = start, hi2 = n_nodes;
    while (lo2 < hi2) { int m = (lo2 + hi2) >> 1; if (batch[m] < g + 1) lo2 = m + 1; else hi2 = m; }
    const int count = lo2 - start;
    if (count <= 0) return;         // block-uniform: safe w.r.t. __syncthreads below

    const int nsweep = (count + 63) >> 6;   // 8 waves x 8 rows per sweep

    // ---- Phase A: sum of squares (cacheable reads + LDS staging of slab head) ----
    float acc = 0.0f;
    for (int s = 0; s < nsweep; ++s) {
        const int base = (s << 6) + (wid << 3);
        if (base + 8 <= count) {
            f32x4 v[8];
            #pragma unroll
            for (int k = 0; k < 8; ++k)
                v[k] = *reinterpret_cast<const f32x4*>(
                    x + (size_t)(start + base + k) * HIDDEN + (size_t)lane * 4);
            if (base + 8 <= STAGE_ROWS) {   // wave-uniform
                #pragma unroll
                for (int k = 0; k < 8; ++k)
                    *reinterpret_cast<f32x4*>(
                        &smem[(base + k) * HIDDEN + lane * 4]) = v[k];
            }
            #pragma unroll
            for (int k = 0; k < 8; ++k)
                acc += v[k].x * v[k].x + v[k].y * v[k].y + v[k].z * v[k].z + v[k].w * v[k].w;
        } else {
            for (int r = base; r < count; ++r) {
                const f32x4 v = *reinterpret_cast<const f32x4*>(
                    x + (size_t)(start + r) * HIDDEN + (size_t)lane * 4);
                acc += v.x * v.x + v.y * v.y + v.z * v.z + v.w * v.w;
            }
        }
    }
    #pragma unroll
    for (int off = 32; off > 0; off >>= 1)
        acc += __shfl_xor(acc, off);
    if (lane == 0) smem[STAGE_ROWS * HIDDEN + wid] = acc;
    __syncthreads();

    float total = 0.0f;
    #pragma unroll
    for (int k = 0; k < 8; ++k) total += smem[STAGE_ROWS * HIDDEN + k];
    const float mean = total / ((float)count * (float)HIDDEN);
    const float rr   = 1.0f / sqrtf(mean + EPS);

    // ---- Phase B: normalize; reverse sweep order; LDS head + NT loads; NT stores ----
    const f32x4 wv = *reinterpret_cast<const f32x4*>(w + (size_t)lane * 4);
    for (int s = nsweep - 1; s >= 0; --s) {
        const int base = (s << 6) + (wid << 3);
        if (base + 8 <= count) {
            f32x4 v[8];
            if (base + 8 <= STAGE_ROWS) {   // staged in phase A by THIS wave
                #pragma unroll
                for (int k = 0; k < 8; ++k)
                    v[k] = *reinterpret_cast<const f32x4*>(
                        &smem[(base + k) * HIDDEN + lane * 4]);
            } else {
                #pragma unroll
                for (int k = 0; k < 8; ++k)
                    v[k] = __builtin_nontemporal_load(reinterpret_cast<const f32x4*>(
                        x + (size_t)(start + base + k) * HIDDEN + (size_t)lane * 4));
            }
            #pragma unroll
            for (int k = 0; k < 8; ++k) {
                f32x4 o;
                o.x = v[k].x * wv.x * rr;
                o.y = v[k].y * wv.y * rr;
                o.z = v[k].z * wv.z * rr;
                o.w = v[k].w * wv.w * rr;
                __builtin_nontemporal_store(o, reinterpret_cast<f32x4*>(
                    out + (size_t)(start + base + k) * HIDDEN + (size_t)lane * 4));
            }
        } else {
            for (int r = base; r < count; ++r) {
                const f32x4 v = __builtin_nontemporal_load(reinterpret_cast<const f32x4*>(
                    x + (size_t)(start + r) * HIDDEN + (size_t)lane * 4));
                f32x4 o;
                o.x = v.x * wv.x * rr;
                o.y = v.y * wv.y * rr;
                o.z = v.z * wv.z * rr;
                o.w = v.w * wv.w * rr;
                __builtin_nontemporal_store(o, reinterpret_cast<f32x4*>(
                    out + (size_t)(start + r) * HIDDEN + (size_t)lane * 4));
            }
        }
    }
}

extern "C" void kernel_launch(void* const* d_in, const int* in_sizes, int n_in,
                              void* d_out, int out_size, void* d_ws, size_t ws_size,
                              hipStream_t stream) {
    const float* x     = (const float*)d_in[0];
    const int*   batch = (const int*)d_in[1];
    const float* w     = (const float*)d_in[2];
    float*       out   = (float*)d_out;
    const int n_nodes  = in_sizes[1];

    // One block per graph; 512 threads = 8 waves; ~152 KB LDS -> 1 block/CU.
    k_fused<<<NGRAPH, 512, 0, stream>>>(x, batch, w, out, n_nodes);
}